// Round 2
// baseline (1355.278 us; speedup 1.0000x reference)
//
#include <hip/hip_runtime.h>
#include <math.h>

// fMRI 3D-GNN forward. Round 2: ALL inputs/outputs are float32 (reference
// dtypes) — round 1 misread them as bf16, injecting NaN weights.

#define NB 8
#define NN 116
#define NN2 (NN*NN)          // 13456
#define KIN 6670
#define FD 16
#define KCHUNK 32
#define KSTEP 209            // ceil(6670/32)

__device__ __forceinline__ float gelu_f(float x) {
  return 0.5f * x * (1.0f + erff(x * 0.70710678118654752f));
}
__device__ __forceinline__ float lrelu(float x) {
  return fmaxf(x, 0.2f * x);
}

// ---------------- K1: x[8,6670] -> xT[6670,8] -----------------------------
__global__ void k_transpose_x(const float* __restrict__ x, float* __restrict__ xT) {
  int idx = blockIdx.x * 256 + threadIdx.x;
  if (idx >= NB * KIN) return;
  int b = idx / KIN, k = idx % KIN;
  xT[k * NB + b] = x[idx];
}

// ------------- K2: split-K big GEMM: logits partials ----------------------
__global__ __launch_bounds__(256) void k_gemm_big(
    const float* __restrict__ xT, const float* __restrict__ Wg,
    float* __restrict__ partial) {
  int c0 = (blockIdx.x * 256 + threadIdx.x) * 4;
  if (c0 >= NN2) return;
  int chunk = blockIdx.y;
  int k0 = chunk * KSTEP;
  int k1 = min(k0 + KSTEP, KIN);
  float acc[NB][4];
#pragma unroll
  for (int b = 0; b < NB; b++)
#pragma unroll
    for (int c = 0; c < 4; c++) acc[b][c] = 0.f;
#pragma unroll 2
  for (int k = k0; k < k1; ++k) {
    const float4 xa = *(const float4*)(xT + k * NB);
    const float4 xb = *(const float4*)(xT + k * NB + 4);
    float4 wv = *(const float4*)(Wg + (size_t)k * NN2 + c0);
    float w[4] = {wv.x, wv.y, wv.z, wv.w};
    float xs[NB] = {xa.x, xa.y, xa.z, xa.w, xb.x, xb.y, xb.z, xb.w};
#pragma unroll
    for (int b = 0; b < NB; b++)
#pragma unroll
      for (int c = 0; c < 4; c++)
        acc[b][c] = fmaf(xs[b], w[c], acc[b][c]);
  }
#pragma unroll
  for (int b = 0; b < NB; b++)
#pragma unroll
    for (int c = 0; c < 4; c++)
      partial[((size_t)chunk * NB + b) * NN2 + c0 + c] = acc[b][c];
}

// ------------- K3: reduce partials + bias + sigmoid -> adj ----------------
__global__ void k_reduce_sigmoid(const float* __restrict__ partial,
                                 const float* __restrict__ bgb,
                                 float* __restrict__ adj) {
  int t = blockIdx.x * 256 + threadIdx.x;
  if (t >= NB * NN2) return;
  int b = t / NN2, rc = t % NN2;
  float s = bgb[rc];
#pragma unroll 8
  for (int ch = 0; ch < KCHUNK; ch++)
    s += partial[((size_t)ch * NB + b) * NN2 + rc];
  adj[t] = 1.0f / (1.0f + expf(-s));
}

// ------------- K4: row stats + feature-embed MLP + LayerNorm -> h0 --------
__global__ void k_stats(const float* __restrict__ adj,
                        const float* __restrict__ feW1, const float* __restrict__ feb1,
                        const float* __restrict__ feW2, const float* __restrict__ feb2,
                        const float* __restrict__ lng, const float* __restrict__ lnb,
                        float* __restrict__ h0) {
  int b = blockIdx.x;
  int r = threadIdx.x;
  if (r >= NN) return;
  const float* row = adj + (size_t)(b * NN + r) * NN;
  float sum = 0.f;
  for (int c = 0; c < NN; c++) { float a = row[c]; sum += (a > 0.5f) ? a : 0.f; }
  float mu = sum / (float)NN;
  float ss = 0.f;
  for (int c = 0; c < NN; c++) {
    float a = row[c]; float m = (a > 0.5f) ? a : 0.f;
    float d = m - mu; ss += d * d;
  }
  float sd = sqrtf(ss / (float)(NN - 1));   // unbiased (N-1)
  float hid[8];
#pragma unroll
  for (int a = 0; a < 8; a++) {
    float z = mu * feW1[a] + sd * feW1[8 + a] + feb1[a];
    hid[a] = gelu_f(z);
  }
  float hf[FD];
  float lm = 0.f;
#pragma unroll
  for (int o = 0; o < FD; o++) {
    float z = feb2[o];
#pragma unroll
    for (int a = 0; a < 8; a++) z += hid[a] * feW2[a * FD + o];
    hf[o] = z; lm += z;
  }
  lm /= (float)FD;
  float lv = 0.f;
#pragma unroll
  for (int o = 0; o < FD; o++) { float d = hf[o] - lm; lv += d * d; }
  lv /= (float)FD;                          // biased (jnp.mean)
  float inv = 1.0f / sqrtf(lv + 1e-5f);
#pragma unroll
  for (int o = 0; o < FD; o++)
    h0[(size_t)(b * NN + r) * FD + o] = (hf[o] - lm) * inv * lng[o] + lnb[o];
}

// ------------- K5: generic fp32 GEMM  C[M,N] = A[M,K]@W[K,N] + bias -------
#define BM 64
#define BN 128
#define BK 16
__global__ __launch_bounds__(256) void k_gemm_xf(
    const float* __restrict__ A, const float* __restrict__ W,
    const float* __restrict__ bias, float* __restrict__ C,
    int M, int Kdim, int Ndim) {
  __shared__ float a_lds[BK][BM];
  __shared__ float b_lds[BK][BN];
  int t = threadIdx.x;
  int m0 = blockIdx.y * BM;
  int n0 = blockIdx.x * BN;
  int tx = t & 15;
  int ty = t >> 4;
  float acc[4][8];
#pragma unroll
  for (int i = 0; i < 4; i++)
#pragma unroll
    for (int j = 0; j < 8; j++) acc[i][j] = 0.f;

  for (int kt = 0; kt < Kdim; kt += BK) {
    {
      int m = t >> 2, kq = (t & 3) << 2;
      float4 v = make_float4(0.f, 0.f, 0.f, 0.f);
      if (m0 + m < M) v = *(const float4*)(A + (size_t)(m0 + m) * Kdim + kt + kq);
      a_lds[kq + 0][m] = v.x; a_lds[kq + 1][m] = v.y;
      a_lds[kq + 2][m] = v.z; a_lds[kq + 3][m] = v.w;
    }
    {
      int k = t >> 4, n8 = (t & 15) << 3;
      const float* wp = W + (size_t)(kt + k) * Ndim + n0 + n8;
      float4 w0 = *(const float4*)(wp);
      float4 w1 = *(const float4*)(wp + 4);
      b_lds[k][n8 + 0] = w0.x; b_lds[k][n8 + 1] = w0.y;
      b_lds[k][n8 + 2] = w0.z; b_lds[k][n8 + 3] = w0.w;
      b_lds[k][n8 + 4] = w1.x; b_lds[k][n8 + 5] = w1.y;
      b_lds[k][n8 + 6] = w1.z; b_lds[k][n8 + 7] = w1.w;
    }
    __syncthreads();
#pragma unroll
    for (int kk = 0; kk < BK; kk++) {
      float4 av  = *(const float4*)(&a_lds[kk][ty << 2]);
      float4 bv0 = *(const float4*)(&b_lds[kk][tx << 3]);
      float4 bv1 = *(const float4*)(&b_lds[kk][(tx << 3) + 4]);
      float am[4] = {av.x, av.y, av.z, av.w};
      float bn_[8] = {bv0.x, bv0.y, bv0.z, bv0.w, bv1.x, bv1.y, bv1.z, bv1.w};
#pragma unroll
      for (int i = 0; i < 4; i++)
#pragma unroll
        for (int j = 0; j < 8; j++)
          acc[i][j] = fmaf(am[i], bn_[j], acc[i][j]);
    }
    __syncthreads();
  }
#pragma unroll
  for (int i = 0; i < 4; i++) {
    int m = m0 + (ty << 2) + i;
    if (m >= M) break;
#pragma unroll
    for (int j = 0; j < 8; j++) {
      int n = n0 + (tx << 3) + j;
      C[(size_t)m * Ndim + n] = acc[i][j] + bias[n];
    }
  }
}

// ------------- K6: GATv2 scores + masked softmax -> alpha -----------------
template<int HH_, int DD_>
__global__ __launch_bounds__(128) void k_attn(
    const float* __restrict__ xl, const float* __restrict__ xr,
    const float* __restrict__ adj, const float* __restrict__ att,
    float* __restrict__ S, int selfloop) {
  constexpr int HD = HH_ * DD_;
  __shared__ float xr_lds[HD];
  __shared__ float att_lds[HD];
  __shared__ float red[2];
  int i = blockIdx.x, b = blockIdx.y;
  int t = threadIdx.x;
  for (int idx = t; idx < HD; idx += 128) {
    xr_lds[idx]  = xr[(size_t)(b * NN + i) * HD + idx];
    att_lds[idx] = att[idx];
  }
  __syncthreads();
  int j = t;
  bool valid = (j < NN);
  int jc = valid ? j : 0;
  // m[b,i,j] = mask[b, src=j, tgt=i] (swapaxes) | (selfloop && i==j)
  bool maskj = valid && ((adj[(size_t)(b * NN + j) * NN + i] > 0.5f) ||
                         (selfloop && (j == i)));
  const float* xlj = xl + (size_t)(b * NN + jc) * HD;
  float eh[HH_];
#pragma unroll
  for (int h = 0; h < HH_; h++) {
    float acc = 0.f;
    int base = h * DD_;
    for (int o = 0; o < DD_; o += 4) {
      float4 v = *(const float4*)(xlj + base + o);
      acc = fmaf(att_lds[base + o + 0], lrelu(xr_lds[base + o + 0] + v.x), acc);
      acc = fmaf(att_lds[base + o + 1], lrelu(xr_lds[base + o + 1] + v.y), acc);
      acc = fmaf(att_lds[base + o + 2], lrelu(xr_lds[base + o + 2] + v.z), acc);
      acc = fmaf(att_lds[base + o + 3], lrelu(xr_lds[base + o + 3] + v.w), acc);
    }
    eh[h] = acc;
  }
#pragma unroll
  for (int h = 0; h < HH_; h++) {
    float v = maskj ? eh[h] : -3.0e38f;
#pragma unroll
    for (int o = 32; o; o >>= 1) v = fmaxf(v, __shfl_xor(v, o, 64));
    __syncthreads();
    if ((t & 63) == 0) red[t >> 6] = v;
    __syncthreads();
    float emax = fmaxf(red[0], red[1]);
    float p = maskj ? expf(eh[h] - emax) : 0.f;
    float s = p;
#pragma unroll
    for (int o = 32; o; o >>= 1) s += __shfl_xor(s, o, 64);
    __syncthreads();
    if ((t & 63) == 0) red[t >> 6] = s;
    __syncthreads();
    float tot = red[0] + red[1];
    float alpha = p / fmaxf(tot, 1e-16f);
    if (valid) S[(((size_t)b * HH_ + h) * NN + i) * NN + j] = alpha;
  }
}

// ------------- K7: out = alpha @ xl, + bias, gelu -> h_next ---------------
template<int HH_, int DD_>
__global__ __launch_bounds__(256) void k_aggr(
    const float* __restrict__ S, const float* __restrict__ xl,
    const float* __restrict__ bias, float* __restrict__ hout) {
  constexpr int HD = HH_ * DD_;
  constexpr int R  = HD / 256;
  __shared__ float al[HH_ * NN];
  int i = blockIdx.x, b = blockIdx.y;
  int t = threadIdx.x;
  for (int idx = t; idx < HH_ * NN; idx += 256) {
    int h = idx / NN, j = idx - h * NN;
    al[idx] = S[(((size_t)b * HH_ + h) * NN + i) * NN + j];
  }
  __syncthreads();
#pragma unroll
  for (int r = 0; r < R; r++) {
    int c = t + (r << 8);
    int h = c / DD_;
    const float* arow = al + h * NN;
    const float* xp = xl + (size_t)b * NN * HD + c;
    float acc = 0.f;
    for (int j = 0; j < NN; j++)
      acc = fmaf(arow[j], xp[(size_t)j * HD], acc);
    hout[(size_t)(b * NN + i) * HD + c] = gelu_f(acc + bias[c]);
  }
}

// ------------- K8: mean-pool + MLP classifier -> out (fp32) ---------------
__global__ __launch_bounds__(256) void k_classifier(
    const float* __restrict__ hfin,   // [8*116][512]
    const float* __restrict__ Wc1, const float* __restrict__ bc1,
    const float* __restrict__ bng, const float* __restrict__ bnb,
    const float* __restrict__ Wc2, const float* __restrict__ bc2,
    float* __restrict__ out) {
  __shared__ float pooled[512];
  __shared__ float cls[256];
  int b = blockIdx.x;
  int t = threadIdx.x;
#pragma unroll
  for (int r = 0; r < 2; r++) {
    int c = t + (r << 8);
    float s = 0.f;
    for (int i = 0; i < NN; i++) s += hfin[(size_t)(b * NN + i) * 512 + c];
    pooled[c] = s / (float)NN;
  }
  __syncthreads();
  {
    int n = t;
    float acc = bc1[n];
    for (int k = 0; k < 512; k++)
      acc = fmaf(pooled[k], Wc1[k * 256 + n], acc);
    float c = acc * (1.0f / sqrtf(1.0f + 1e-5f)) * bng[n] + bnb[n];
    cls[n] = gelu_f(c);
  }
  __syncthreads();
  if (t < 128) {
    int jj = t >> 6, lane = t & 63;
    float s = 0.f;
#pragma unroll
    for (int w = 0; w < 4; w++) {
      int k = lane + (w << 6);
      s += cls[k] * Wc2[k * 2 + jj];
    }
#pragma unroll
    for (int o = 32; o; o >>= 1) s += __shfl_xor(s, o, 64);
    if (lane == 0) out[b * 2 + jj] = s + bc2[jj];
  }
}

// --------------------------------------------------------------------------
extern "C" void kernel_launch(void* const* d_in, const int* in_sizes, int n_in,
                              void* d_out, int out_size, void* d_ws, size_t ws_size,
                              hipStream_t stream) {
  const float* x    = (const float*)d_in[0];
  const float* Wgb  = (const float*)d_in[1];
  const float* bgb  = (const float*)d_in[2];
  const float* feW1 = (const float*)d_in[3];
  const float* feb1 = (const float*)d_in[4];
  const float* feW2 = (const float*)d_in[5];
  const float* feb2 = (const float*)d_in[6];
  const float* lng  = (const float*)d_in[7];
  const float* lnb  = (const float*)d_in[8];
  const float* Wl[3]   = {(const float*)d_in[9],  (const float*)d_in[15], (const float*)d_in[21]};
  const float* bl[3]   = {(const float*)d_in[10], (const float*)d_in[16], (const float*)d_in[22]};
  const float* Wr[3]   = {(const float*)d_in[11], (const float*)d_in[17], (const float*)d_in[23]};
  const float* br[3]   = {(const float*)d_in[12], (const float*)d_in[18], (const float*)d_in[24]};
  const float* att[3]  = {(const float*)d_in[13], (const float*)d_in[19], (const float*)d_in[25]};
  const float* bias[3] = {(const float*)d_in[14], (const float*)d_in[20], (const float*)d_in[26]};
  const float* Wc1 = (const float*)d_in[27];
  const float* bc1 = (const float*)d_in[28];
  const float* bng = (const float*)d_in[29];
  const float* bnb = (const float*)d_in[30];
  const float* Wc2 = (const float*)d_in[31];
  const float* bc2 = (const float*)d_in[32];

  float* ws = (float*)d_ws;
  float* xT  = ws;               // 53,360 (round up 53,376)
  float* adj = ws + 53376;       // 107,648
  float* scratch = ws + 161024;  // overlay region
  float* partial = scratch;            // 32*8*13456 = 3,444,736
  float* hA      = scratch;            // 928*1024 (partial dead by then)
  float* hB      = hA + 950272;
  float* xlbuf   = hB + 950272;
  float* xrbuf   = xlbuf + 950272;
  float* Sbuf    = xrbuf + 950272;     // 8*8*116*116 = 861,184

  k_transpose_x<<<dim3((NB * KIN + 255) / 256), 256, 0, stream>>>(x, xT);
  k_gemm_big<<<dim3(14, KCHUNK), 256, 0, stream>>>(xT, Wgb, partial);
  k_reduce_sigmoid<<<dim3((NB * NN2 + 255) / 256), 256, 0, stream>>>(partial, bgb, adj);
  k_stats<<<dim3(NB), 128, 0, stream>>>(adj, feW1, feb1, feW2, feb2, lng, lnb, hA);

  dim3 ab(NN, NB);
  // ---- layer 0: 16 -> 8 heads x 128, no self loops ----
  {
    dim3 gg(1024 / BN, (928 + BM - 1) / BM);
    k_gemm_xf<<<gg, 256, 0, stream>>>(hA, Wl[0], bl[0], xlbuf, 928, 16, 1024);
    k_gemm_xf<<<gg, 256, 0, stream>>>(hA, Wr[0], br[0], xrbuf, 928, 16, 1024);
    k_attn<8, 128><<<ab, 128, 0, stream>>>(xlbuf, xrbuf, adj, att[0], Sbuf, 0);
    k_aggr<8, 128><<<ab, 256, 0, stream>>>(Sbuf, xlbuf, bias[0], hB);
  }
  // ---- layer 1: 1024 -> 4 heads x 256, self loops ----
  {
    dim3 gg(1024 / BN, (928 + BM - 1) / BM);
    k_gemm_xf<<<gg, 256, 0, stream>>>(hB, Wl[1], bl[1], xlbuf, 928, 1024, 1024);
    k_gemm_xf<<<gg, 256, 0, stream>>>(hB, Wr[1], br[1], xrbuf, 928, 1024, 1024);
    k_attn<4, 256><<<ab, 128, 0, stream>>>(xlbuf, xrbuf, adj, att[1], Sbuf, 1);
    k_aggr<4, 256><<<ab, 256, 0, stream>>>(Sbuf, xlbuf, bias[1], hA);
  }
  // ---- layer 2: 1024 -> 1 head x 512, self loops ----
  {
    dim3 gg(512 / BN, (928 + BM - 1) / BM);
    k_gemm_xf<<<gg, 256, 0, stream>>>(hA, Wl[2], bl[2], xlbuf, 928, 1024, 512);
    k_gemm_xf<<<gg, 256, 0, stream>>>(hA, Wr[2], br[2], xrbuf, 928, 1024, 512);
    k_attn<1, 512><<<ab, 128, 0, stream>>>(xlbuf, xrbuf, adj, att[2], Sbuf, 1);
    k_aggr<1, 512><<<ab, 256, 0, stream>>>(Sbuf, xlbuf, bias[2], hB);
  }

  k_classifier<<<dim3(NB), 256, 0, stream>>>(hB, Wc1, bc1, bng, bnb, Wc2, bc2,
                                             (float*)d_out);
}

// Round 3
// 972.283 us; speedup vs baseline: 1.3939x; 1.3939x over previous
//
#include <hip/hip_runtime.h>
#include <math.h>

// fMRI 3D-GNN forward, fp32. Round 3: fused dual GEMM (Wl+Wr share A-tiles,
// 2x parallelism) + fused attention(score+softmax+aggregate) per layer.

#define NB 8
#define NN 116
#define NN2 (NN*NN)          // 13456
#define KIN 6670
#define FD 16
#define KCHUNK 32
#define KSTEP 209            // ceil(6670/32)

__device__ __forceinline__ float gelu_f(float x) {
  return 0.5f * x * (1.0f + erff(x * 0.70710678118654752f));
}
__device__ __forceinline__ float lrelu(float x) {
  return fmaxf(x, 0.2f * x);
}

// ---------------- K1: x[8,6670] -> xT[6670,8] -----------------------------
__global__ void k_transpose_x(const float* __restrict__ x, float* __restrict__ xT) {
  int idx = blockIdx.x * 256 + threadIdx.x;
  if (idx >= NB * KIN) return;
  int b = idx / KIN, k = idx % KIN;
  xT[k * NB + b] = x[idx];
}

// ------------- K2: split-K big GEMM (HBM-bound: 360 MB W_gb) --------------
__global__ __launch_bounds__(256) void k_gemm_big(
    const float* __restrict__ xT, const float* __restrict__ Wg,
    float* __restrict__ partial) {
  int c0 = (blockIdx.x * 256 + threadIdx.x) * 4;
  if (c0 >= NN2) return;
  int chunk = blockIdx.y;
  int k0 = chunk * KSTEP;
  int k1 = min(k0 + KSTEP, KIN);
  float acc[NB][4];
#pragma unroll
  for (int b = 0; b < NB; b++)
#pragma unroll
    for (int c = 0; c < 4; c++) acc[b][c] = 0.f;
#pragma unroll 2
  for (int k = k0; k < k1; ++k) {
    const float4 xa = *(const float4*)(xT + k * NB);
    const float4 xb = *(const float4*)(xT + k * NB + 4);
    float4 wv = *(const float4*)(Wg + (size_t)k * NN2 + c0);
    float w[4] = {wv.x, wv.y, wv.z, wv.w};
    float xs[NB] = {xa.x, xa.y, xa.z, xa.w, xb.x, xb.y, xb.z, xb.w};
#pragma unroll
    for (int b = 0; b < NB; b++)
#pragma unroll
      for (int c = 0; c < 4; c++)
        acc[b][c] = fmaf(xs[b], w[c], acc[b][c]);
  }
#pragma unroll
  for (int b = 0; b < NB; b++)
#pragma unroll
    for (int c = 0; c < 4; c++)
      partial[((size_t)chunk * NB + b) * NN2 + c0 + c] = acc[b][c];
}

// ------------- K3: reduce partials + bias + sigmoid -> adj ----------------
__global__ void k_reduce_sigmoid(const float* __restrict__ partial,
                                 const float* __restrict__ bgb,
                                 float* __restrict__ adj) {
  int t = blockIdx.x * 256 + threadIdx.x;
  if (t >= NB * NN2) return;
  int b = t / NN2, rc = t % NN2;
  float s = bgb[rc];
#pragma unroll 8
  for (int ch = 0; ch < KCHUNK; ch++)
    s += partial[((size_t)ch * NB + b) * NN2 + rc];
  adj[t] = 1.0f / (1.0f + expf(-s));
}

// ------------- K4: row stats + FE MLP + LayerNorm -> h0 -------------------
__global__ void k_stats(const float* __restrict__ adj,
                        const float* __restrict__ feW1, const float* __restrict__ feb1,
                        const float* __restrict__ feW2, const float* __restrict__ feb2,
                        const float* __restrict__ lng, const float* __restrict__ lnb,
                        float* __restrict__ h0) {
  int b = blockIdx.x;
  int r = threadIdx.x;
  if (r >= NN) return;
  const float* row = adj + (size_t)(b * NN + r) * NN;
  float sum = 0.f;
  for (int c = 0; c < NN; c++) { float a = row[c]; sum += (a > 0.5f) ? a : 0.f; }
  float mu = sum / (float)NN;
  float ss = 0.f;
  for (int c = 0; c < NN; c++) {
    float a = row[c]; float m = (a > 0.5f) ? a : 0.f;
    float d = m - mu; ss += d * d;
  }
  float sd = sqrtf(ss / (float)(NN - 1));   // unbiased (N-1)
  float hid[8];
#pragma unroll
  for (int a = 0; a < 8; a++) {
    float z = mu * feW1[a] + sd * feW1[8 + a] + feb1[a];
    hid[a] = gelu_f(z);
  }
  float hf[FD];
  float lm = 0.f;
#pragma unroll
  for (int o = 0; o < FD; o++) {
    float z = feb2[o];
#pragma unroll
    for (int a = 0; a < 8; a++) z += hid[a] * feW2[a * FD + o];
    hf[o] = z; lm += z;
  }
  lm /= (float)FD;
  float lv = 0.f;
#pragma unroll
  for (int o = 0; o < FD; o++) { float d = hf[o] - lm; lv += d * d; }
  lv /= (float)FD;                          // biased (jnp.mean)
  float inv = 1.0f / sqrtf(lv + 1e-5f);
#pragma unroll
  for (int o = 0; o < FD; o++)
    h0[(size_t)(b * NN + r) * FD + o] = (hf[o] - lm) * inv * lng[o] + lnb[o];
}

// ------------- K5: dual GEMM  xl = A@W0+b0, xr = A@W1+b1 ------------------
// Tile 64(M) x 64(N) x 32(K); logical grid.x spans 2N columns.
#define GM 64
#define GN 64
#define GK 32
__global__ __launch_bounds__(256) void k_gemm_dual(
    const float* __restrict__ A,
    const float* __restrict__ W0, const float* __restrict__ b0,
    const float* __restrict__ W1, const float* __restrict__ b1,
    float* __restrict__ C0, float* __restrict__ C1,
    int M, int K, int N) {
  int nc = blockIdx.x * GN;
  const float* W    = (nc < N) ? W0 : W1;
  const float* bias = (nc < N) ? b0 : b1;
  float*       C    = (nc < N) ? C0 : C1;
  int n0 = (nc < N) ? nc : nc - N;
  int m0 = blockIdx.y * GM;

  __shared__ float a_s[GK][GM];       // 8 KB
  __shared__ float b_s[GK][GN + 4];   // 8.5 KB (pad kills write conflicts)
  int t = threadIdx.x;
  int tx = t & 15, ty = t >> 4;       // out: n = tx*4, m = ty*4
  float acc[4][4];
#pragma unroll
  for (int i = 0; i < 4; i++)
#pragma unroll
    for (int j = 0; j < 4; j++) acc[i][j] = 0.f;

  for (int kt = 0; kt < K; kt += GK) {
    // stage A (transposed): thread m = t&63, k8 = (t>>6)*8
    {
      int m = t & 63, k8 = (t >> 6) * 8;
      int gm = m0 + m;
      float va[8];
      if (gm < M && (kt + k8 + 8) <= K) {
        float4 v0 = *(const float4*)(A + (size_t)gm * K + kt + k8);
        float4 v1 = *(const float4*)(A + (size_t)gm * K + kt + k8 + 4);
        va[0]=v0.x; va[1]=v0.y; va[2]=v0.z; va[3]=v0.w;
        va[4]=v1.x; va[5]=v1.y; va[6]=v1.z; va[7]=v1.w;
      } else {
#pragma unroll
        for (int e = 0; e < 8; e++) {
          int gk = kt + k8 + e;
          va[e] = (gm < M && gk < K) ? A[(size_t)gm * K + gk] : 0.f;
        }
      }
#pragma unroll
      for (int e = 0; e < 8; e++) a_s[k8 + e][m] = va[e];
    }
    // stage B: thread k = t>>3, n8 = (t&7)*8
    {
      int k = t >> 3, n8 = (t & 7) * 8;
      int gk = kt + k;
      float4 w0 = make_float4(0.f,0.f,0.f,0.f), w1 = w0;
      if (gk < K) {
        const float* wp = W + (size_t)gk * N + n0 + n8;
        w0 = *(const float4*)(wp);
        w1 = *(const float4*)(wp + 4);
      }
      b_s[k][n8 + 0] = w0.x; b_s[k][n8 + 1] = w0.y;
      b_s[k][n8 + 2] = w0.z; b_s[k][n8 + 3] = w0.w;
      b_s[k][n8 + 4] = w1.x; b_s[k][n8 + 5] = w1.y;
      b_s[k][n8 + 6] = w1.z; b_s[k][n8 + 7] = w1.w;
    }
    __syncthreads();
#pragma unroll
    for (int kk = 0; kk < GK; kk++) {
      float4 av = *(const float4*)(&a_s[kk][ty << 2]);
      float4 bv = *(const float4*)(&b_s[kk][tx << 2]);
      float am[4] = {av.x, av.y, av.z, av.w};
      float bn_[4] = {bv.x, bv.y, bv.z, bv.w};
#pragma unroll
      for (int i = 0; i < 4; i++)
#pragma unroll
        for (int j = 0; j < 4; j++)
          acc[i][j] = fmaf(am[i], bn_[j], acc[i][j]);
    }
    __syncthreads();
  }
#pragma unroll
  for (int i = 0; i < 4; i++) {
    int m = m0 + (ty << 2) + i;
    if (m >= M) break;
#pragma unroll
    for (int j = 0; j < 4; j++) {
      int n = n0 + (tx << 2) + j;
      C[(size_t)m * N + n] = acc[i][j] + bias[n];
    }
  }
}

// ------------- K6: fused GATv2 scores + softmax + aggregate + gelu --------
// block = (target i, batch b), 256 threads. alpha lives in LDS only.
template<int HH_, int DD_>
__global__ __launch_bounds__(256) void k_attn_aggr(
    const float* __restrict__ xl, const float* __restrict__ xr,
    const float* __restrict__ adj, const float* __restrict__ att,
    const float* __restrict__ bias, float* __restrict__ hout, int selfloop) {
  constexpr int HD = HH_ * DD_;
  __shared__ float xr_lds[HD];
  __shared__ float att_lds[HD];
  __shared__ float e_lds[HH_][128];
  __shared__ float maskf[128];
  int i = blockIdx.x, b = blockIdx.y;
  int t = threadIdx.x;

  for (int idx = t; idx < HD; idx += 256) {
    xr_lds[idx]  = xr[(size_t)(b * NN + i) * HD + idx];
    att_lds[idx] = att[idx];
  }
  if (t < 128) {
    bool mj = (t < NN) && ((adj[(size_t)(b * NN + t) * NN + i] > 0.5f) ||
                           (selfloop && (t == i)));
    maskf[t] = mj ? 1.f : 0.f;
  }
  __syncthreads();

  // ---- phase 1: raw scores e[h][j] ----
  int half = t >> 7;          // 0 or 1
  int j = t & 127;
  bool valid = (j < NN);
  const float* xlj = xl + (size_t)(b * NN + (valid ? j : 0)) * HD;
  if (HH_ >= 2) {
    constexpr int HHH = HH_ / 2;
#pragma unroll
    for (int hh = 0; hh < HHH; hh++) {
      int h = half * HHH + hh;
      int base = h * DD_;
      float acc = 0.f;
      for (int o = 0; o < DD_; o += 4) {
        float4 v = *(const float4*)(xlj + base + o);
        acc = fmaf(att_lds[base + o + 0], lrelu(xr_lds[base + o + 0] + v.x), acc);
        acc = fmaf(att_lds[base + o + 1], lrelu(xr_lds[base + o + 1] + v.y), acc);
        acc = fmaf(att_lds[base + o + 2], lrelu(xr_lds[base + o + 2] + v.z), acc);
        acc = fmaf(att_lds[base + o + 3], lrelu(xr_lds[base + o + 3] + v.w), acc);
      }
      if (valid) e_lds[h][j] = acc;
    }
    __syncthreads();
  } else {
    // HH==1: halves split DD, combine in LDS
    constexpr int DH = DD_ / 2;
    int base = half * DH;
    float acc = 0.f;
    for (int o = 0; o < DH; o += 4) {
      float4 v = *(const float4*)(xlj + base + o);
      acc = fmaf(att_lds[base + o + 0], lrelu(xr_lds[base + o + 0] + v.x), acc);
      acc = fmaf(att_lds[base + o + 1], lrelu(xr_lds[base + o + 1] + v.y), acc);
      acc = fmaf(att_lds[base + o + 2], lrelu(xr_lds[base + o + 2] + v.z), acc);
      acc = fmaf(att_lds[base + o + 3], lrelu(xr_lds[base + o + 3] + v.w), acc);
    }
    if (half == 0 && valid) e_lds[0][j] = acc;
    __syncthreads();
    if (half == 1 && valid) e_lds[0][j] += acc;
    __syncthreads();
  }

  // ---- phase 2: masked softmax per head (wave w owns heads w, w+4, ...) ----
  {
    int w = t >> 6, lane = t & 63;
#pragma unroll
    for (int hh = 0; hh < (HH_ + 3) / 4; hh++) {
      int h = w + hh * 4;
      if (h < HH_) {
        float mk0 = maskf[lane], mk1 = maskf[lane + 64];
        float e0 = e_lds[h][lane], e1 = e_lds[h][lane + 64];
        float v = fmaxf(mk0 != 0.f ? e0 : -3.0e38f,
                        mk1 != 0.f ? e1 : -3.0e38f);
#pragma unroll
        for (int o = 32; o; o >>= 1) v = fmaxf(v, __shfl_xor(v, o, 64));
        float p0 = (mk0 != 0.f) ? expf(e0 - v) : 0.f;
        float p1 = (mk1 != 0.f) ? expf(e1 - v) : 0.f;
        float s = p0 + p1;
#pragma unroll
        for (int o = 32; o; o >>= 1) s += __shfl_xor(s, o, 64);
        float inv = 1.0f / fmaxf(s, 1e-16f);
        e_lds[h][lane]      = p0 * inv;
        e_lds[h][lane + 64] = p1 * inv;
      }
    }
  }
  __syncthreads();

  // ---- phase 3: out[c] = sum_j alpha[h(c)][j] * xl[b,j,c]; bias + gelu ----
  for (int c = t; c < HD; c += 256) {
    int h = c / DD_;
    const float* xp = xl + (size_t)b * NN * HD + c;
    const float* arow = e_lds[h];
    float acc = 0.f;
#pragma unroll 4
    for (int jj = 0; jj < NN; jj++)
      acc = fmaf(arow[jj], xp[(size_t)jj * HD], acc);
    hout[(size_t)(b * NN + i) * HD + c] = gelu_f(acc + bias[c]);
  }
}

// ------------- K7: mean-pool + classifier ---------------------------------
__global__ __launch_bounds__(256) void k_classifier(
    const float* __restrict__ hfin,   // [8*116][512]
    const float* __restrict__ Wc1, const float* __restrict__ bc1,
    const float* __restrict__ bng, const float* __restrict__ bnb,
    const float* __restrict__ Wc2, const float* __restrict__ bc2,
    float* __restrict__ out) {
  __shared__ float pooled[512];
  __shared__ float cls[256];
  int b = blockIdx.x;
  int t = threadIdx.x;
#pragma unroll
  for (int r = 0; r < 2; r++) {
    int c = t + (r << 8);
    float s = 0.f;
    for (int i = 0; i < NN; i++) s += hfin[(size_t)(b * NN + i) * 512 + c];
    pooled[c] = s / (float)NN;
  }
  __syncthreads();
  {
    int n = t;
    float acc = bc1[n];
    for (int k = 0; k < 512; k++)
      acc = fmaf(pooled[k], Wc1[k * 256 + n], acc);
    float c = acc * (1.0f / sqrtf(1.0f + 1e-5f)) * bng[n] + bnb[n];
    cls[n] = gelu_f(c);
  }
  __syncthreads();
  if (t < 128) {
    int jj = t >> 6, lane = t & 63;
    float s = 0.f;
#pragma unroll
    for (int w = 0; w < 4; w++) {
      int k = lane + (w << 6);
      s += cls[k] * Wc2[k * 2 + jj];
    }
#pragma unroll
    for (int o = 32; o; o >>= 1) s += __shfl_xor(s, o, 64);
    if (lane == 0) out[b * 2 + jj] = s + bc2[jj];
  }
}

// --------------------------------------------------------------------------
extern "C" void kernel_launch(void* const* d_in, const int* in_sizes, int n_in,
                              void* d_out, int out_size, void* d_ws, size_t ws_size,
                              hipStream_t stream) {
  const float* x    = (const float*)d_in[0];
  const float* Wgb  = (const float*)d_in[1];
  const float* bgb  = (const float*)d_in[2];
  const float* feW1 = (const float*)d_in[3];
  const float* feb1 = (const float*)d_in[4];
  const float* feW2 = (const float*)d_in[5];
  const float* feb2 = (const float*)d_in[6];
  const float* lng  = (const float*)d_in[7];
  const float* lnb  = (const float*)d_in[8];
  const float* Wl[3]   = {(const float*)d_in[9],  (const float*)d_in[15], (const float*)d_in[21]};
  const float* bl[3]   = {(const float*)d_in[10], (const float*)d_in[16], (const float*)d_in[22]};
  const float* Wr[3]   = {(const float*)d_in[11], (const float*)d_in[17], (const float*)d_in[23]};
  const float* br[3]   = {(const float*)d_in[12], (const float*)d_in[18], (const float*)d_in[24]};
  const float* att[3]  = {(const float*)d_in[13], (const float*)d_in[19], (const float*)d_in[25]};
  const float* bias[3] = {(const float*)d_in[14], (const float*)d_in[20], (const float*)d_in[26]};
  const float* Wc1 = (const float*)d_in[27];
  const float* bc1 = (const float*)d_in[28];
  const float* bng = (const float*)d_in[29];
  const float* bnb = (const float*)d_in[30];
  const float* Wc2 = (const float*)d_in[31];
  const float* bc2 = (const float*)d_in[32];

  float* ws = (float*)d_ws;
  float* xT  = ws;               // 53,360 (rounded 53,376)
  float* adj = ws + 53376;       // 107,648
  float* scratch = ws + 161024;  // overlay region
  float* partial = scratch;            // 32*8*13456 = 3,444,736 (dead after K3)
  float* hA      = scratch;            // 928*1024
  float* hB      = hA + 950272;
  float* xlbuf   = hB + 950272;
  float* xrbuf   = xlbuf + 950272;

  k_transpose_x<<<dim3((NB * KIN + 255) / 256), 256, 0, stream>>>(x, xT);
  k_gemm_big<<<dim3(14, KCHUNK), 256, 0, stream>>>(xT, Wgb, partial);
  k_reduce_sigmoid<<<dim3((NB * NN2 + 255) / 256), 256, 0, stream>>>(partial, bgb, adj);
  k_stats<<<dim3(NB), 128, 0, stream>>>(adj, feW1, feb1, feW2, feb2, lng, lnb, hA);

  dim3 ab(NN, NB);
  // ---- layer 0: 16 -> 8x128, no self loops ----
  k_gemm_dual<<<dim3(2 * 1024 / GN, 15), 256, 0, stream>>>(
      hA, Wl[0], bl[0], Wr[0], br[0], xlbuf, xrbuf, 928, 16, 1024);
  k_attn_aggr<8, 128><<<ab, 256, 0, stream>>>(xlbuf, xrbuf, adj, att[0], bias[0], hB, 0);
  // ---- layer 1: 1024 -> 4x256, self loops ----
  k_gemm_dual<<<dim3(2 * 1024 / GN, 15), 256, 0, stream>>>(
      hB, Wl[1], bl[1], Wr[1], br[1], xlbuf, xrbuf, 928, 1024, 1024);
  k_attn_aggr<4, 256><<<ab, 256, 0, stream>>>(xlbuf, xrbuf, adj, att[1], bias[1], hA, 1);
  // ---- layer 2: 1024 -> 1x512, self loops ----
  k_gemm_dual<<<dim3(2 * 512 / GN, 15), 256, 0, stream>>>(
      hA, Wl[2], bl[2], Wr[2], br[2], xlbuf, xrbuf, 928, 1024, 512);
  k_attn_aggr<1, 512><<<ab, 256, 0, stream>>>(xlbuf, xrbuf, adj, att[2], bias[2], hB, 1);

  k_classifier<<<dim3(NB), 256, 0, stream>>>(hB, Wc1, bc1, bng, bnb, Wc2, bc2,
                                             (float*)d_out);
}